// Round 2
// baseline (979.466 us; speedup 1.0000x reference)
//
#include <hip/hip_runtime.h>
#include <stdint.h>

// MFMA fragment types (guide §3: bf16 16x16x32 -> 8x short A/B, 4x float C/D)
typedef short bf16x8 __attribute__((ext_vector_type(8)));
typedef float f32x4 __attribute__((ext_vector_type(4)));

__device__ __forceinline__ float bf2f(uint16_t u) {
  union { uint32_t i; float f; } v; v.i = ((uint32_t)u) << 16; return v.f;
}
__device__ __forceinline__ uint16_t f2bf(float f) {
  union { float f; uint32_t i; } v; v.f = f;
  uint32_t x = v.i;
  return (uint16_t)((x + 0x7fffu + ((x >> 16) & 1u)) >> 16); // RNE
}

__global__ void zero_kernel(int* cnt, int* cur, int n) {
  int i = blockIdx.x * 256 + threadIdx.x;
  if (i < n) { cnt[i] = 0; cur[i] = 0; }
}

__global__ void count_kernel(const int* __restrict__ dst, int* __restrict__ cnt, int E) {
  int e = blockIdx.x * 256 + threadIdx.x;
  if (e < E) atomicAdd(&cnt[dst[e]], 1);
}

// Single-block exclusive scan over cnt[0..n) -> row_ptr[0..n]
__global__ void scan_kernel(const int* __restrict__ cnt, int* __restrict__ row_ptr, int n) {
  __shared__ int wsum[4];
  const int t = threadIdx.x, lane = t & 63, wid = t >> 6;
  int carry = 0;
  for (int base = 0; base < n; base += 256) {
    int i = base + t;
    int v = (i < n) ? cnt[i] : 0;
    int x = v;
#pragma unroll
    for (int off = 1; off < 64; off <<= 1) {
      int y = __shfl_up(x, off, 64);
      if (lane >= off) x += y;
    }
    if (lane == 63) wsum[wid] = x;
    __syncthreads();
    int woff = 0;
    for (int w = 0; w < wid; w++) woff += wsum[w];
    int total = wsum[0] + wsum[1] + wsum[2] + wsum[3];
    if (i < n) row_ptr[i] = carry + woff + (x - v);
    carry += total;
    __syncthreads();
  }
  if (t == 0) row_ptr[n] = carry;
}

__global__ void fill_kernel(const int* __restrict__ src, const int* __restrict__ dst,
                            const int* __restrict__ row_ptr, int* __restrict__ cur,
                            int* __restrict__ csr, int E) {
  int e = blockIdx.x * 256 + threadIdx.x;
  if (e < E) {
    int d = dst[e];
    int pos = row_ptr[d] + atomicAdd(&cur[d], 1);
    csr[pos] = src[e];
  }
}

// Build Wcat[layer][o][kc] (bf16 pairs; k<128 from W_l, k>=128 from W_r) from fp32 W.
__global__ void wcvt_kernel(const float* __restrict__ Wl1, const float* __restrict__ Wr1,
                            const float* __restrict__ Wl2, const float* __restrict__ Wr2,
                            uint32_t* __restrict__ Wcat) {
  int e = blockIdx.x * 256 + threadIdx.x; // 2 * 128 * 128 u32 (each = 2 bf16)
  if (e >= 32768) return;
  int L = e >> 14, r = e & 16383;
  int o = r >> 7, kc = r & 127;
  const float* W = (kc < 64) ? (L ? Wl2 : Wl1) : (L ? Wr2 : Wr1);
  int k2 = (kc & 63) * 2;
  float a = W[o * 128 + k2];
  float b = W[o * 128 + k2 + 1];
  Wcat[e] = (uint32_t)f2bf(a) | ((uint32_t)f2bf(b) << 16);
}

// h-part gather: A[n][128+k] = bf16(emb[x[n]][k]); one wave per node, 2 fp32 -> 1 u32 per lane
__global__ void gather_kernel(const int* __restrict__ x, const float* __restrict__ emb,
                              uint32_t* __restrict__ A, int N) {
  int gw = (blockIdx.x * 256 + threadIdx.x) >> 6;
  int lane = threadIdx.x & 63;
  if (gw >= N) return;
  long row = x[gw];
  float2 v = *(const float2*)(emb + row * 128 + lane * 2);
  A[(long)gw * 128 + 64 + lane] = (uint32_t)f2bf(v.x) | ((uint32_t)f2bf(v.y) << 16);
}

// Mean aggregation: reads A[:,128:256] (bf16 h), writes A[:,0:128] (bf16 agg), fp32 accum
__global__ void agg_kernel(uint32_t* __restrict__ A, const int* __restrict__ row_ptr,
                           const int* __restrict__ csr, int N) {
  int gw = (blockIdx.x * 256 + threadIdx.x) >> 6;
  int lane = threadIdx.x & 63;
  if (gw >= N) return;
  int b = row_ptr[gw], e = row_ptr[gw + 1];
  float ax = 0.f, ay = 0.f;
  for (int i = b; i < e; i++) {
    int s = csr[i];
    uint32_t v = A[(long)s * 128 + 64 + lane];
    ax += bf2f((uint16_t)(v & 0xffff));
    ay += bf2f((uint16_t)(v >> 16));
  }
  int deg = e - b;
  float sc = 1.0f / (float)(deg > 0 ? deg : 1);
  A[(long)gw * 128 + lane] = (uint32_t)f2bf(ax * sc) | ((uint32_t)f2bf(ay * sc) << 16);
}

// out = relu(A[n,0:256] @ Wcat^T + bias); block tile 128(M)x128(N), K=256.
// Wave tile 64x64 = 4x4 MFMA 16x16x32 tiles. W in LDS, XOR bank-swizzled for
// conflict-free ds_read_b128 B-fragment loads. FINAL stores fp32 to d_out.
template <bool FINAL>
__global__ __launch_bounds__(256) void gemm_kernel(const uint16_t* __restrict__ A,
                                                   const uint32_t* __restrict__ Wcat,
                                                   const float* __restrict__ bias,
                                                   uint16_t* __restrict__ outH, // A2 base (bf16 h-part)
                                                   float* __restrict__ outF,    // d_out fp32 [N][128]
                                                   int N) {
  __shared__ uint32_t lds[16384]; // 64 KiB: W as [o][kc] u32, group-swizzled
  for (int e = threadIdx.x; e < 16384; e += 256) {
    int o = e >> 7, kc = e & 127;
    int g = kc >> 2, c = kc & 3;
    lds[(o << 7) | ((g ^ (o & 7)) << 2) | c] = Wcat[e];
  }
  __syncthreads();
  int lane = threadIdx.x & 63, wv = threadIdx.x >> 6;
  int wm = wv >> 1, wo = wv & 1;
  int ol = lane & 15, q = lane >> 4;
  int nb = blockIdx.x * 128 + wm * 64;
  f32x4 acc[4][4] = {};
#pragma unroll
  for (int ks = 0; ks < 8; ks++) {
    bf16x8 a[4], bfr[4];
#pragma unroll
    for (int mt = 0; mt < 4; mt++) {
      long n = nb + mt * 16 + ol;
      a[mt] = *(const bf16x8*)(A + n * 256 + ks * 32 + q * 8);
    }
#pragma unroll
    for (int ot = 0; ot < 4; ot++) {
      int o = wo * 64 + ot * 16 + ol;
      int g = ks * 4 + q;
      bfr[ot] = *(const bf16x8*)&lds[(o << 7) | ((g ^ (o & 7)) << 2)];
    }
#pragma unroll
    for (int mt = 0; mt < 4; mt++)
#pragma unroll
      for (int ot = 0; ot < 4; ot++)
        acc[mt][ot] = __builtin_amdgcn_mfma_f32_16x16x32_bf16(a[mt], bfr[ot], acc[mt][ot], 0, 0, 0);
  }
  // C/D layout: col(=o) = lane&15, row(=node) = (lane>>4)*4 + reg
#pragma unroll
  for (int ot = 0; ot < 4; ot++) {
    int o = wo * 64 + ot * 16 + ol;
    float bv = bias[o];
#pragma unroll
    for (int mt = 0; mt < 4; mt++) {
#pragma unroll
      for (int r = 0; r < 4; r++) {
        int n = nb + mt * 16 + q * 4 + r;
        if (n < N) {
          float v = acc[mt][ot][r] + bv;
          v = v > 0.f ? v : 0.f;
          if (FINAL) outF[(long)n * 128 + o] = v;
          else outH[(long)n * 256 + 128 + o] = f2bf(v);
        }
      }
    }
  }
}

extern "C" void kernel_launch(void* const* d_in, const int* in_sizes, int n_in,
                              void* d_out, int out_size, void* d_ws, size_t ws_size,
                              hipStream_t stream) {
  const int* x = (const int*)d_in[0];
  const int* edge = (const int*)d_in[1];
  const float* emb = (const float*)d_in[2];
  const float* W1l = (const float*)d_in[3];
  const float* b1 = (const float*)d_in[4];
  const float* W1r = (const float*)d_in[5];
  const float* W2l = (const float*)d_in[6];
  const float* b2 = (const float*)d_in[7];
  const float* W2r = (const float*)d_in[8];
  const int N = in_sizes[0];
  const int E = in_sizes[1] / 2;
  const int* srcE = edge;
  const int* dstE = edge + E;

  const int Npad = ((N + 127) / 128) * 128;
  char* p = (char*)d_ws;
  uint16_t* A1 = (uint16_t*)p; p += (size_t)Npad * 256 * 2;  // [Npad][256] bf16: [agg | h]
  uint16_t* A2 = (uint16_t*)p; p += (size_t)Npad * 256 * 2;
  uint32_t* Wcat = (uint32_t*)p; p += (size_t)2 * 16384 * 4;
  int* cnt = (int*)p;     p += (((size_t)N * 4 + 255) / 256) * 256;
  int* cur = (int*)p;     p += (((size_t)N * 4 + 255) / 256) * 256;
  int* row_ptr = (int*)p; p += (((size_t)(N + 1) * 4 + 255) / 256) * 256;
  int* csr = (int*)p;     p += (((size_t)E * 4 + 255) / 256) * 256;

  zero_kernel<<<(N + 255) / 256, 256, 0, stream>>>(cnt, cur, N);
  count_kernel<<<(E + 255) / 256, 256, 0, stream>>>(dstE, cnt, E);
  scan_kernel<<<1, 256, 0, stream>>>(cnt, row_ptr, N);
  fill_kernel<<<(E + 255) / 256, 256, 0, stream>>>(srcE, dstE, row_ptr, cur, csr, E);
  wcvt_kernel<<<128, 256, 0, stream>>>(W1l, W1r, W2l, W2r, Wcat);
  gather_kernel<<<(N + 3) / 4, 256, 0, stream>>>(x, emb, (uint32_t*)A1, N);
  agg_kernel<<<(N + 3) / 4, 256, 0, stream>>>((uint32_t*)A1, row_ptr, csr, N);
  gemm_kernel<false><<<Npad / 128, 256, 0, stream>>>(A1, Wcat, b1, A2, nullptr, N);
  agg_kernel<<<(N + 3) / 4, 256, 0, stream>>>((uint32_t*)A2, row_ptr, csr, N);
  gemm_kernel<true><<<Npad / 128, 256, 0, stream>>>(A2, Wcat + 16384, b2, nullptr, (float*)d_out, N);
}

// Round 3
// 808.051 us; speedup vs baseline: 1.2121x; 1.2121x over previous
//
#include <hip/hip_runtime.h>
#include <stdint.h>

// MFMA fragment types (guide §3: bf16 16x16x32 -> 8x short A/B, 4x float C/D)
typedef short bf16x8 __attribute__((ext_vector_type(8)));
typedef float f32x4 __attribute__((ext_vector_type(4)));

__device__ __forceinline__ float bf2f(uint16_t u) {
  union { uint32_t i; float f; } v; v.i = ((uint32_t)u) << 16; return v.f;
}
__device__ __forceinline__ uint16_t f2bf(float f) {
  union { float f; uint32_t i; } v; v.f = f;
  uint32_t x = v.i;
  return (uint16_t)((x + 0x7fffu + ((x >> 16) & 1u)) >> 16); // RNE
}

__global__ void zero_kernel(int* cnt, int* cur, int* gcur, int n) {
  int i = blockIdx.x * 256 + threadIdx.x;
  if (i < n) { cnt[i] = 0; cur[i] = 0; }
  if (i == 0) *gcur = 0;
}

__global__ void count_kernel(const int* __restrict__ dst, int* __restrict__ cnt, int E) {
  int e = blockIdx.x * 256 + threadIdx.x;
  if (e < E) atomicAdd(&cnt[dst[e]], 1);
}

// Disjoint segment allocation WITHOUT a global sorted scan: per-wave exclusive
// shuffle-scan of 64 counts + ONE atomicAdd of the wave total on a global
// cursor. Order of segments in csr[] is irrelevant (mean is commutative).
__global__ void alloc_kernel(const int* __restrict__ cnt, int* __restrict__ row_start,
                             int* __restrict__ gcur, int N) {
  int i = blockIdx.x * 256 + threadIdx.x;
  int lane = threadIdx.x & 63;
  int v = (i < N) ? cnt[i] : 0;
  int x = v;
#pragma unroll
  for (int off = 1; off < 64; off <<= 1) {
    int y = __shfl_up(x, off, 64);
    if (lane >= off) x += y;
  }
  int total = __shfl(x, 63, 64);
  int base = 0;
  if (lane == 63) base = atomicAdd(gcur, total);
  base = __shfl(base, 63, 64);
  if (i < N) row_start[i] = base + x - v;  // exclusive prefix within wave
}

__global__ void fill_kernel(const int* __restrict__ src, const int* __restrict__ dst,
                            const int* __restrict__ row_start, int* __restrict__ cur,
                            int* __restrict__ csr, int E) {
  int e = blockIdx.x * 256 + threadIdx.x;
  if (e < E) {
    int d = dst[e];
    int pos = row_start[d] + atomicAdd(&cur[d], 1);
    csr[pos] = src[e];
  }
}

// Build Wcat[layer][o][kc] (bf16 pairs; k<128 from W_l, k>=128 from W_r) from fp32 W.
__global__ void wcvt_kernel(const float* __restrict__ Wl1, const float* __restrict__ Wr1,
                            const float* __restrict__ Wl2, const float* __restrict__ Wr2,
                            uint32_t* __restrict__ Wcat) {
  int e = blockIdx.x * 256 + threadIdx.x; // 2 * 128 * 128 u32 (each = 2 bf16)
  if (e >= 32768) return;
  int L = e >> 14, r = e & 16383;
  int o = r >> 7, kc = r & 127;
  const float* W = (kc < 64) ? (L ? Wl2 : Wl1) : (L ? Wr2 : Wr1);
  int k2 = (kc & 63) * 2;
  float a = W[o * 128 + k2];
  float b = W[o * 128 + k2 + 1];
  Wcat[e] = (uint32_t)f2bf(a) | ((uint32_t)f2bf(b) << 16);
}

// h-part gather: A[n][128+k] = bf16(emb[x[n]][k]); one wave per node, 2 fp32 -> 1 u32 per lane
__global__ void gather_kernel(const int* __restrict__ x, const float* __restrict__ emb,
                              uint32_t* __restrict__ A, int N) {
  int gw = (blockIdx.x * 256 + threadIdx.x) >> 6;
  int lane = threadIdx.x & 63;
  if (gw >= N) return;
  long row = x[gw];
  float2 v = *(const float2*)(emb + row * 128 + lane * 2);
  A[(long)gw * 128 + 64 + lane] = (uint32_t)f2bf(v.x) | ((uint32_t)f2bf(v.y) << 16);
}

// Mean aggregation: reads A[:,128:256] (bf16 h), writes A[:,0:128] (bf16 agg), fp32 accum.
// One wave per node; neighbor loop pairwise-unrolled for load ILP.
__global__ void agg_kernel(uint32_t* __restrict__ A, const int* __restrict__ row_start,
                           const int* __restrict__ cnt, const int* __restrict__ csr, int N) {
  int gw = (blockIdx.x * 256 + threadIdx.x) >> 6;
  int lane = threadIdx.x & 63;
  if (gw >= N) return;
  int b = row_start[gw];
  int deg = cnt[gw];
  int e = b + deg;
  float ax = 0.f, ay = 0.f;
  int i = b;
  for (; i + 1 < e; i += 2) {
    int s0 = csr[i], s1 = csr[i + 1];
    uint32_t v0 = A[(long)s0 * 128 + 64 + lane];
    uint32_t v1 = A[(long)s1 * 128 + 64 + lane];
    ax += bf2f((uint16_t)(v0 & 0xffff)) + bf2f((uint16_t)(v1 & 0xffff));
    ay += bf2f((uint16_t)(v0 >> 16)) + bf2f((uint16_t)(v1 >> 16));
  }
  if (i < e) {
    uint32_t v = A[(long)csr[i] * 128 + 64 + lane];
    ax += bf2f((uint16_t)(v & 0xffff));
    ay += bf2f((uint16_t)(v >> 16));
  }
  float sc = 1.0f / (float)(deg > 0 ? deg : 1);
  A[(long)gw * 128 + lane] = (uint32_t)f2bf(ax * sc) | ((uint32_t)f2bf(ay * sc) << 16);
}

// out = relu(A[n,0:256] @ Wcat^T + bias); block tile 128(M)x128(N), K=256.
// Wave tile 64x64 = 4x4 MFMA 16x16x32 tiles. W in LDS, XOR bank-swizzled for
// conflict-free ds_read_b128 B-fragment loads. FINAL stores fp32 to d_out.
template <bool FINAL>
__global__ __launch_bounds__(256) void gemm_kernel(const uint16_t* __restrict__ A,
                                                   const uint32_t* __restrict__ Wcat,
                                                   const float* __restrict__ bias,
                                                   uint16_t* __restrict__ outH, // A2 base (bf16 h-part)
                                                   float* __restrict__ outF,    // d_out fp32 [N][128]
                                                   int N) {
  __shared__ uint32_t lds[16384]; // 64 KiB: W as [o][kc] u32, group-swizzled
  for (int e = threadIdx.x; e < 16384; e += 256) {
    int o = e >> 7, kc = e & 127;
    int g = kc >> 2, c = kc & 3;
    lds[(o << 7) | ((g ^ (o & 7)) << 2) | c] = Wcat[e];
  }
  __syncthreads();
  int lane = threadIdx.x & 63, wv = threadIdx.x >> 6;
  int wm = wv >> 1, wo = wv & 1;
  int ol = lane & 15, q = lane >> 4;
  int nb = blockIdx.x * 128 + wm * 64;
  f32x4 acc[4][4] = {};
#pragma unroll
  for (int ks = 0; ks < 8; ks++) {
    bf16x8 a[4], bfr[4];
#pragma unroll
    for (int mt = 0; mt < 4; mt++) {
      long n = nb + mt * 16 + ol;
      a[mt] = *(const bf16x8*)(A + n * 256 + ks * 32 + q * 8);
    }
#pragma unroll
    for (int ot = 0; ot < 4; ot++) {
      int o = wo * 64 + ot * 16 + ol;
      int g = ks * 4 + q;
      bfr[ot] = *(const bf16x8*)&lds[(o << 7) | ((g ^ (o & 7)) << 2)];
    }
#pragma unroll
    for (int mt = 0; mt < 4; mt++)
#pragma unroll
      for (int ot = 0; ot < 4; ot++)
        acc[mt][ot] = __builtin_amdgcn_mfma_f32_16x16x32_bf16(a[mt], bfr[ot], acc[mt][ot], 0, 0, 0);
  }
  // C/D layout: col(=o) = lane&15, row(=node) = (lane>>4)*4 + reg
#pragma unroll
  for (int ot = 0; ot < 4; ot++) {
    int o = wo * 64 + ot * 16 + ol;
    float bv = bias[o];
#pragma unroll
    for (int mt = 0; mt < 4; mt++) {
#pragma unroll
      for (int r = 0; r < 4; r++) {
        int n = nb + mt * 16 + q * 4 + r;
        if (n < N) {
          float v = acc[mt][ot][r] + bv;
          v = v > 0.f ? v : 0.f;
          if (FINAL) outF[(long)n * 128 + o] = v;
          else outH[(long)n * 256 + 128 + o] = f2bf(v);
        }
      }
    }
  }
}

extern "C" void kernel_launch(void* const* d_in, const int* in_sizes, int n_in,
                              void* d_out, int out_size, void* d_ws, size_t ws_size,
                              hipStream_t stream) {
  const int* x = (const int*)d_in[0];
  const int* edge = (const int*)d_in[1];
  const float* emb = (const float*)d_in[2];
  const float* W1l = (const float*)d_in[3];
  const float* b1 = (const float*)d_in[4];
  const float* W1r = (const float*)d_in[5];
  const float* W2l = (const float*)d_in[6];
  const float* b2 = (const float*)d_in[7];
  const float* W2r = (const float*)d_in[8];
  const int N = in_sizes[0];
  const int E = in_sizes[1] / 2;
  const int* srcE = edge;
  const int* dstE = edge + E;

  const int Npad = ((N + 127) / 128) * 128;
  char* p = (char*)d_ws;
  uint16_t* A1 = (uint16_t*)p; p += (size_t)Npad * 256 * 2;  // [Npad][256] bf16: [agg | h]
  uint16_t* A2 = (uint16_t*)p; p += (size_t)Npad * 256 * 2;
  uint32_t* Wcat = (uint32_t*)p; p += (size_t)2 * 16384 * 4;
  int* cnt = (int*)p;       p += (((size_t)N * 4 + 255) / 256) * 256;
  int* cur = (int*)p;       p += (((size_t)N * 4 + 255) / 256) * 256;
  int* row_start = (int*)p; p += (((size_t)N * 4 + 255) / 256) * 256;
  int* csr = (int*)p;       p += (((size_t)E * 4 + 255) / 256) * 256;
  int* gcur = (int*)p;      p += 256;

  zero_kernel<<<(N + 255) / 256, 256, 0, stream>>>(cnt, cur, gcur, N);
  count_kernel<<<(E + 255) / 256, 256, 0, stream>>>(dstE, cnt, E);
  alloc_kernel<<<(N + 255) / 256, 256, 0, stream>>>(cnt, row_start, gcur, N);
  fill_kernel<<<(E + 255) / 256, 256, 0, stream>>>(srcE, dstE, row_start, cur, csr, E);
  wcvt_kernel<<<128, 256, 0, stream>>>(W1l, W1r, W2l, W2r, Wcat);
  gather_kernel<<<(N + 3) / 4, 256, 0, stream>>>(x, emb, (uint32_t*)A1, N);
  agg_kernel<<<(N + 3) / 4, 256, 0, stream>>>((uint32_t*)A1, row_start, cnt, csr, N);
  gemm_kernel<false><<<Npad / 128, 256, 0, stream>>>(A1, Wcat, b1, A2, nullptr, N);
  agg_kernel<<<(N + 3) / 4, 256, 0, stream>>>((uint32_t*)A2, row_start, cnt, csr, N);
  gemm_kernel<true><<<Npad / 128, 256, 0, stream>>>(A2, Wcat + 16384, b2, nullptr, (float*)d_out, N);
}